// Round 1
// baseline (128.812 us; speedup 1.0000x reference)
//
#include <hip/hip_runtime.h>
#include <math.h>

// FFT-based circular conv: y[b,h,:] = irfft(rfft(x[b,h,:]) * rfft(k[h,:]))
// N = 4096 real points -> M = 2048 complex FFT via even/odd packing.

#define FFT_M 2048
#define FFT_N 4096
#define LOG2M 11
#define NT 256
#define KF_LD 2049  // rfft length N/2+1, complex elements per kf row

struct Lds {
  float re0[FFT_M];
  float im0[FFT_M];
  float re1[FFT_M];
  float im1[FFT_M];
  float twr[FFT_M / 2];
  float twi[FFT_M / 2];
};

__device__ __forceinline__ void build_twiddles(Lds& L) {
#pragma unroll
  for (int u = 0; u < (FFT_M / 2) / NT; ++u) {
    int j = threadIdx.x + u * NT;
    float sn, cs;
    sincosf(6.2831853071795864769f * (float)j / (float)FFT_M, &sn, &cs);
    L.twr[j] = cs;
    L.twi[j] = sn;
  }
}

// Stockham radix-2 DIF. Input in (re0,im0); after LOG2M (odd) stages the
// result is in (re1,im1), natural order. SIGN=-1 forward DFT, +1 inverse
// (unnormalized). Caller must __syncthreads() before calling.
template <int SIGN>
__device__ __forceinline__ void block_fft(Lds& L) {
  float* xr = L.re0;
  float* xi = L.im0;
  float* yr = L.re1;
  float* yi = L.im1;
#pragma unroll
  for (int stage = 0; stage < LOG2M; ++stage) {
    const int s = 1 << stage;
#pragma unroll
    for (int u = 0; u < (FFT_M / 2) / NT; ++u) {
      const int t = threadIdx.x + u * NT;
      const int q = t & (s - 1);
      const int tw = t - q;        // p*s -> twiddle table index (W_M^{p*s})
      const int o = tw + tw + q;   // q + 2*s*p
      float ar = xr[t], ai = xi[t];
      float br = xr[t + FFT_M / 2], bi = xi[t + FFT_M / 2];
      float wr = L.twr[tw];
      float wi = (SIGN > 0) ? L.twi[tw] : -L.twi[tw];
      float dr = ar - br, di = ai - bi;
      yr[o] = ar + br;
      yi[o] = ai + bi;
      yr[o + s] = dr * wr - di * wi;
      yi[o + s] = dr * wi + di * wr;
    }
    __syncthreads();
    float* tp;
    tp = xr; xr = yr; yr = tp;
    tp = xi; xi = yi; yi = tp;
  }
}

// From Z = FFT_M(x[2m] + i*x[2m+1]) in (re1,im1), produce the real-input
// spectrum values X[kk] (p) and X[FFT_M - kk] (q), kk in [0, 1024].
// For kk==0 the partner is X[M] (Nyquist); for kk==1024 p==q.
__device__ __forceinline__ void unpack_pair(const Lds& L, int kk, float& Xpr,
                                            float& Xpi, float& Xqr, float& Xqi) {
  const int kc = (FFT_M - kk) & (FFT_M - 1);
  float zkr = L.re1[kk], zki = L.im1[kk];
  float zcr = L.re1[kc], zci = L.im1[kc];
  float Er = 0.5f * (zkr + zcr), Ei = 0.5f * (zki - zci);
  float Or = 0.5f * (zki + zci), Oi = 0.5f * (zcr - zkr);
  float sn, cs;
  sincosf(1.5339807878856412e-3f * (float)kk, &sn, &cs);  // 2*pi*kk/4096
  // X[kk]   = E + (cs - i sn) * O
  Xpr = Er + cs * Or + sn * Oi;
  Xpi = Ei + cs * Oi - sn * Or;
  // X[M-kk] = conj(E) + (-cs - i sn) * conj(O)
  Xqr = Er - cs * Or - sn * Oi;
  Xqi = -Ei + cs * Oi - sn * Or;
}

__global__ __launch_bounds__(NT) void kfft_kernel(const float* __restrict__ kin,
                                                  float2* __restrict__ kf) {
  __shared__ Lds L;
  const int h = blockIdx.x;
  const float2* krow = (const float2*)(kin + (size_t)h * FFT_N);
#pragma unroll
  for (int u = 0; u < FFT_M / NT; ++u) {
    int j = threadIdx.x + u * NT;
    float2 v = krow[j];
    L.re0[j] = v.x;
    L.im0[j] = v.y;
  }
  build_twiddles(L);
  __syncthreads();
  block_fft<-1>(L);
  float2* kfrow = kf + (size_t)h * KF_LD;
#pragma unroll
  for (int u = 0; u < 4; ++u) {
    int kk = threadIdx.x + u * NT;  // 0..1023
    float Xpr, Xpi, Xqr, Xqi;
    unpack_pair(L, kk, Xpr, Xpi, Xqr, Xqi);
    kfrow[kk] = make_float2(Xpr, Xpi);
    kfrow[FFT_M - kk] = make_float2(Xqr, Xqi);  // kk=0 -> index 2048 (Nyquist)
  }
  if (threadIdx.x == 0) {
    float Xpr, Xpi, Xqr, Xqi;
    unpack_pair(L, FFT_M / 2, Xpr, Xpi, Xqr, Xqi);
    kfrow[FFT_M / 2] = make_float2(Xpr, Xpi);
  }
}

__global__ __launch_bounds__(NT) void conv_kernel(const float* __restrict__ x,
                                                  const float2* __restrict__ kf,
                                                  float* __restrict__ y, int H) {
  __shared__ Lds L;
  const int row = blockIdx.x;
  const int h = row % H;
  const float2* xrow = (const float2*)(x + (size_t)row * FFT_N);
#pragma unroll
  for (int u = 0; u < FFT_M / NT; ++u) {
    int j = threadIdx.x + u * NT;
    float2 v = xrow[j];
    L.re0[j] = v.x;
    L.im0[j] = v.y;
  }
  build_twiddles(L);
  __syncthreads();
  block_fft<-1>(L);  // Z in (re1,im1)

  const float2* kfrow = kf + (size_t)h * KF_LD;
  // Unpack X, multiply by Kf, repack Z2 for the inverse transform into (re0,im0).
#pragma unroll
  for (int u = 0; u < 4; ++u) {
    int kk = threadIdx.x + u * NT;  // 0..1023
    float Xpr, Xpi, Xqr, Xqi;
    unpack_pair(L, kk, Xpr, Xpi, Xqr, Xqi);
    float2 Kp = kfrow[kk];
    float2 Kq = kfrow[FFT_M - kk];
    float Ypr = Xpr * Kp.x - Xpi * Kp.y;
    float Ypi = Xpr * Kp.y + Xpi * Kp.x;
    float Yqr = Xqr * Kq.x - Xqi * Kq.y;
    float Yqi = Xqr * Kq.y + Xqi * Kq.x;
    // E' = (Yp + conj(Yq))/2 ; D = (Yp - conj(Yq))/2
    float Epr = 0.5f * (Ypr + Yqr), Epi = 0.5f * (Ypi - Yqi);
    float Dr = 0.5f * (Ypr - Yqr), Di = 0.5f * (Ypi + Yqi);
    float sn, cs;
    sincosf(1.5339807878856412e-3f * (float)kk, &sn, &cs);  // 2*pi*kk/4096
    // Z2[kk]   = E' + i*conj(w)*D,  w = (cs, -sn)
    L.re0[kk] = Epr - cs * Di - sn * Dr;
    L.im0[kk] = Epi + cs * Dr - sn * Di;
    if (kk != 0) {
      // Z2[M-kk] = conj(E') + i*w*conj(D)
      L.re0[FFT_M - kk] = Epr + cs * Di + sn * Dr;
      L.im0[FFT_M - kk] = -Epi + cs * Dr - sn * Di;
    }
  }
  if (threadIdx.x == 0) {  // kk = 1024: Z2[1024] = conj(Y[1024])
    const int kk = FFT_M / 2;
    float Xpr, Xpi, Xqr, Xqi;
    unpack_pair(L, kk, Xpr, Xpi, Xqr, Xqi);
    float2 Kp = kfrow[kk];
    float Ypr = Xpr * Kp.x - Xpi * Kp.y;
    float Ypi = Xpr * Kp.y + Xpi * Kp.x;
    L.re0[kk] = Ypr;
    L.im0[kk] = -Ypi;
  }
  __syncthreads();
  block_fft<1>(L);  // z2 in (re1,im1)

  const float s = 1.0f / (float)FFT_M;
  float2* yrow = (float2*)(y + (size_t)row * FFT_N);
#pragma unroll
  for (int u = 0; u < FFT_M / NT; ++u) {
    int j = threadIdx.x + u * NT;
    yrow[j] = make_float2(L.re1[j] * s, L.im1[j] * s);
  }
}

extern "C" void kernel_launch(void* const* d_in, const int* in_sizes, int n_in,
                              void* d_out, int out_size, void* d_ws, size_t ws_size,
                              hipStream_t stream) {
  const float* x = (const float*)d_in[0];
  const float* kin = (const float*)d_in[1];
  float* y = (float*)d_out;
  const int H = in_sizes[1] / FFT_N;   // 768
  const int BH = in_sizes[0] / FFT_N;  // 6144 rows
  float2* kf = (float2*)d_ws;          // 768 * 2049 * 8 B = 12.6 MB
  hipLaunchKernelGGL(kfft_kernel, dim3(H), dim3(NT), 0, stream, kin, kf);
  hipLaunchKernelGGL(conv_kernel, dim3(BH), dim3(NT), 0, stream, x, kf, y, H);
}

// Round 2
// 65.946 us; speedup vs baseline: 1.9533x; 1.9533x over previous
//
#include <hip/hip_runtime.h>
#include <math.h>

// FFT circular conv: y[b,h,:] = irfft(rfft(x[b,h,:]) * rfft(k[h,:])), N=4096.
// M=2048 complex FFT via even/odd packing. Mixed-radix Stockham: 8,8,8,4.

#define FFT_M 2048
#define FFT_N 4096
#define NT 256
#define KF_LD 2049
// LDS index swizzle: breaks power-of-2 stride bank conflicts; bijective.
#define SW(a) ((a) ^ (((a) >> 5) & 31))

#define C_SQRT1_2 0.70710678118654752f
#define TWO_PI_OVER_M 3.0679615757712823e-3f  // 2*pi/2048
#define TWO_PI_OVER_N 1.5339807878856412e-3f  // 2*pi/4096

struct Lds {
  float r0[FFT_M], i0[FFT_M], r1[FFT_M], i1[FFT_M];  // 32 KB
};

// One Stockham radix-8 stage, stride S (compile-time). 256 threads = N/8
// butterflies. Reads x[t + 256*j], writes y[q + 8*S*p + S*m] * W_M^{S*p*m}.
template <int SIGN, int S>
__device__ __forceinline__ void stage_r8(const float* xr, const float* xi,
                                         float* yr, float* yi) {
  const unsigned t = threadIdx.x;
  const int q = (int)(t & (S - 1));
  const int p = (int)(t / S);
  float ar[8], ai[8];
#pragma unroll
  for (int j = 0; j < 8; ++j) {
    const int idx = SW((int)t + 256 * j);
    ar[j] = xr[idx];
    ai[j] = xi[idx];
  }
  // even DFT4 over a0,a2,a4,a6
  float s0r = ar[0] + ar[4], s0i = ai[0] + ai[4];
  float s1r = ar[0] - ar[4], s1i = ai[0] - ai[4];
  float s2r = ar[2] + ar[6], s2i = ai[2] + ai[6];
  float s3r = ar[2] - ar[6], s3i = ai[2] - ai[6];
  float E0r = s0r + s2r, E0i = s0i + s2i;
  float E2r = s0r - s2r, E2i = s0i - s2i;
  float E1r, E1i, E3r, E3i;
  if (SIGN < 0) {
    E1r = s1r + s3i; E1i = s1i - s3r;
    E3r = s1r - s3i; E3i = s1i + s3r;
  } else {
    E1r = s1r - s3i; E1i = s1i + s3r;
    E3r = s1r + s3i; E3i = s1i - s3r;
  }
  // odd DFT4 over a1,a3,a5,a7
  float u0r = ar[1] + ar[5], u0i = ai[1] + ai[5];
  float u1r = ar[1] - ar[5], u1i = ai[1] - ai[5];
  float u2r = ar[3] + ar[7], u2i = ai[3] + ai[7];
  float u3r = ar[3] - ar[7], u3i = ai[3] - ai[7];
  float O0r = u0r + u2r, O0i = u0i + u2i;
  float O2r = u0r - u2r, O2i = u0i - u2i;
  float O1r, O1i, O3r, O3i;
  if (SIGN < 0) {
    O1r = u1r + u3i; O1i = u1i - u3r;
    O3r = u1r - u3i; O3i = u1i + u3r;
  } else {
    O1r = u1r - u3i; O1i = u1i + u3r;
    O3r = u1r + u3i; O3i = u1i - u3r;
  }
  // twist odd outputs by w8^m
  float t1r, t1i, t2r, t2i, t3r, t3i;
  if (SIGN < 0) {
    t1r = C_SQRT1_2 * (O1r + O1i); t1i = C_SQRT1_2 * (O1i - O1r);
    t2r = O2i;                      t2i = -O2r;
    t3r = C_SQRT1_2 * (O3i - O3r); t3i = -C_SQRT1_2 * (O3r + O3i);
  } else {
    t1r = C_SQRT1_2 * (O1r - O1i); t1i = C_SQRT1_2 * (O1i + O1r);
    t2r = -O2i;                     t2i = O2r;
    t3r = -C_SQRT1_2 * (O3r + O3i); t3i = C_SQRT1_2 * (O3r - O3i);
  }
  float br[8], bi[8];
  br[0] = E0r + O0r; bi[0] = E0i + O0i;
  br[4] = E0r - O0r; bi[4] = E0i - O0i;
  br[1] = E1r + t1r; bi[1] = E1i + t1i;
  br[5] = E1r - t1r; bi[5] = E1i - t1i;
  br[2] = E2r + t2r; bi[2] = E2i + t2i;
  br[6] = E2r - t2r; bi[6] = E2i - t2i;
  br[3] = E3r + t3r; bi[3] = E3i + t3i;
  br[7] = E3r - t3r; bi[7] = E3i - t3i;

  const int ob = q + 8 * S * p;
  {
    const int idx = SW(ob);
    yr[idx] = br[0];
    yi[idx] = bi[0];
  }
  const float ang = (float)SIGN * TWO_PI_OVER_M * (float)(p * S);
  float w1i, w1r;
  __sincosf(ang, &w1i, &w1r);
  float cwr = w1r, cwi = w1i;
#pragma unroll
  for (int m = 1; m < 8; ++m) {
    const int idx = SW(ob + S * m);
    yr[idx] = br[m] * cwr - bi[m] * cwi;
    yi[idx] = br[m] * cwi + bi[m] * cwr;
    if (m < 7) {
      const float nr = cwr * w1r - cwi * w1i;
      const float ni = cwr * w1i + cwi * w1r;
      cwr = nr;
      cwi = ni;
    }
  }
}

// Final radix-4 stage, S=512: p==0 so twiddle-free. 512 butterflies.
template <int SIGN>
__device__ __forceinline__ void stage_r4_final(const float* xr, const float* xi,
                                               float* yr, float* yi) {
#pragma unroll
  for (int u = 0; u < 2; ++u) {
    const int t = (int)threadIdx.x + u * NT;  // 0..511
    float a0r = xr[SW(t)],        a0i = xi[SW(t)];
    float a1r = xr[SW(t + 512)],  a1i = xi[SW(t + 512)];
    float a2r = xr[SW(t + 1024)], a2i = xi[SW(t + 1024)];
    float a3r = xr[SW(t + 1536)], a3i = xi[SW(t + 1536)];
    float s0r = a0r + a2r, s0i = a0i + a2i;
    float s1r = a0r - a2r, s1i = a0i - a2i;
    float s2r = a1r + a3r, s2i = a1i + a3i;
    float s3r = a1r - a3r, s3i = a1i - a3i;
    yr[SW(t)] = s0r + s2r;         yi[SW(t)] = s0i + s2i;
    yr[SW(t + 1024)] = s0r - s2r;  yi[SW(t + 1024)] = s0i - s2i;
    if (SIGN < 0) {
      yr[SW(t + 512)]  = s1r + s3i;  yi[SW(t + 512)]  = s1i - s3r;
      yr[SW(t + 1536)] = s1r - s3i;  yi[SW(t + 1536)] = s1i + s3r;
    } else {
      yr[SW(t + 512)]  = s1r - s3i;  yi[SW(t + 512)]  = s1i + s3r;
      yr[SW(t + 1536)] = s1r + s3i;  yi[SW(t + 1536)] = s1i - s3r;
    }
  }
}

// In: data in (r0,i0). Out: transform in (r0,i0), natural order (unnormalized).
template <int SIGN>
__device__ __forceinline__ void fft2048(Lds& L) {
  __syncthreads();
  stage_r8<SIGN, 1>(L.r0, L.i0, L.r1, L.i1);
  __syncthreads();
  stage_r8<SIGN, 8>(L.r1, L.i1, L.r0, L.i0);
  __syncthreads();
  stage_r8<SIGN, 64>(L.r0, L.i0, L.r1, L.i1);
  __syncthreads();
  stage_r4_final<SIGN>(L.r1, L.i1, L.r0, L.i0);
  __syncthreads();
}

// From Z = FFT_M(x[2m] + i*x[2m+1]) in (zr,zi), produce the real-input
// spectrum X[kk] (p) and X[FFT_M - kk] (q), kk in [0, 1024].
__device__ __forceinline__ void unpack_pair(const float* zr, const float* zi,
                                            int kk, float& Xpr, float& Xpi,
                                            float& Xqr, float& Xqi) {
  const int kc = (FFT_M - kk) & (FFT_M - 1);
  const float zkr = zr[SW(kk)], zki = zi[SW(kk)];
  const float zcr = zr[SW(kc)], zci = zi[SW(kc)];
  const float Er = 0.5f * (zkr + zcr), Ei = 0.5f * (zki - zci);
  const float Or = 0.5f * (zki + zci), Oi = 0.5f * (zcr - zkr);
  float sn, cs;
  __sincosf(TWO_PI_OVER_N * (float)kk, &sn, &cs);
  Xpr = Er + cs * Or + sn * Oi;
  Xpi = Ei + cs * Oi - sn * Or;
  Xqr = Er - cs * Or - sn * Oi;
  Xqi = -Ei + cs * Oi - sn * Or;
}

__global__ __launch_bounds__(NT) void kfft_kernel(const float* __restrict__ kin,
                                                  float2* __restrict__ kf) {
  __shared__ Lds L;
  const int h = blockIdx.x;
  const float4* krow = (const float4*)(kin + (size_t)h * FFT_N);
#pragma unroll
  for (int u = 0; u < FFT_N / (4 * NT); ++u) {
    const int j = (int)threadIdx.x + u * NT;
    const float4 v = krow[j];
    L.r0[SW(2 * j)] = v.x;     L.i0[SW(2 * j)] = v.y;
    L.r0[SW(2 * j + 1)] = v.z; L.i0[SW(2 * j + 1)] = v.w;
  }
  fft2048<-1>(L);
  const float scale = 1.0f / (float)FFT_M;  // folded inverse-FFT normalization
  float2* kfrow = kf + (size_t)h * KF_LD;
#pragma unroll
  for (int u = 0; u < 4; ++u) {
    const int kk = (int)threadIdx.x + u * NT;  // 0..1023
    float Xpr, Xpi, Xqr, Xqi;
    unpack_pair(L.r0, L.i0, kk, Xpr, Xpi, Xqr, Xqi);
    kfrow[kk] = make_float2(Xpr * scale, Xpi * scale);
    kfrow[FFT_M - kk] = make_float2(Xqr * scale, Xqi * scale);  // kk=0 -> Nyquist
  }
  if (threadIdx.x == 0) {
    float Xpr, Xpi, Xqr, Xqi;
    unpack_pair(L.r0, L.i0, FFT_M / 2, Xpr, Xpi, Xqr, Xqi);
    kfrow[FFT_M / 2] = make_float2(Xpr * scale, Xpi * scale);
  }
}

__global__ __launch_bounds__(NT) void conv_kernel(const float* __restrict__ x,
                                                  const float2* __restrict__ kf,
                                                  float* __restrict__ y, int H) {
  __shared__ Lds L;
  const int row = blockIdx.x;
  const int h = row % H;
  const float4* xrow = (const float4*)(x + (size_t)row * FFT_N);
#pragma unroll
  for (int u = 0; u < FFT_N / (4 * NT); ++u) {
    const int j = (int)threadIdx.x + u * NT;
    const float4 v = xrow[j];
    L.r0[SW(2 * j)] = v.x;     L.i0[SW(2 * j)] = v.y;
    L.r0[SW(2 * j + 1)] = v.z; L.i0[SW(2 * j + 1)] = v.w;
  }
  fft2048<-1>(L);  // Z in (r0,i0)

  const float2* kfrow = kf + (size_t)h * KF_LD;
  // Unpack X, multiply by Kf, repack Z2 in place (pairs disjoint per thread).
#pragma unroll
  for (int u = 0; u < 4; ++u) {
    const int kk = (int)threadIdx.x + u * NT;  // 0..1023
    float Xpr, Xpi, Xqr, Xqi;
    unpack_pair(L.r0, L.i0, kk, Xpr, Xpi, Xqr, Xqi);
    const float2 Kp = kfrow[kk];
    const float2 Kq = kfrow[FFT_M - kk];
    const float Ypr = Xpr * Kp.x - Xpi * Kp.y;
    const float Ypi = Xpr * Kp.y + Xpi * Kp.x;
    const float Yqr = Xqr * Kq.x - Xqi * Kq.y;
    const float Yqi = Xqr * Kq.y + Xqi * Kq.x;
    const float Epr = 0.5f * (Ypr + Yqr), Epi = 0.5f * (Ypi - Yqi);
    const float Dr = 0.5f * (Ypr - Yqr), Di = 0.5f * (Ypi + Yqi);
    float sn, cs;
    __sincosf(TWO_PI_OVER_N * (float)kk, &sn, &cs);
    L.r0[SW(kk)] = Epr - cs * Di - sn * Dr;
    L.i0[SW(kk)] = Epi + cs * Dr - sn * Di;
    if (kk != 0) {
      L.r0[SW(FFT_M - kk)] = Epr + cs * Di + sn * Dr;
      L.i0[SW(FFT_M - kk)] = -Epi + cs * Dr - sn * Di;
    }
  }
  if (threadIdx.x == 0) {  // kk = 1024: Z2[1024] = conj(Y[1024])
    const int kk = FFT_M / 2;
    float Xpr, Xpi, Xqr, Xqi;
    unpack_pair(L.r0, L.i0, kk, Xpr, Xpi, Xqr, Xqi);
    const float2 Kp = kfrow[kk];
    const float Ypr = Xpr * Kp.x - Xpi * Kp.y;
    const float Ypi = Xpr * Kp.y + Xpi * Kp.x;
    L.r0[SW(kk)] = Ypr;
    L.i0[SW(kk)] = -Ypi;
  }
  fft2048<1>(L);  // y (scaled via kf) in (r0,i0)

  float4* yrow = (float4*)(y + (size_t)row * FFT_N);
#pragma unroll
  for (int u = 0; u < FFT_N / (4 * NT); ++u) {
    const int j = (int)threadIdx.x + u * NT;
    float4 v;
    v.x = L.r0[SW(2 * j)];     v.y = L.i0[SW(2 * j)];
    v.z = L.r0[SW(2 * j + 1)]; v.w = L.i0[SW(2 * j + 1)];
    yrow[j] = v;
  }
}

extern "C" void kernel_launch(void* const* d_in, const int* in_sizes, int n_in,
                              void* d_out, int out_size, void* d_ws, size_t ws_size,
                              hipStream_t stream) {
  const float* x = (const float*)d_in[0];
  const float* kin = (const float*)d_in[1];
  float* y = (float*)d_out;
  const int H = in_sizes[1] / FFT_N;   // 768
  const int BH = in_sizes[0] / FFT_N;  // 6144
  float2* kf = (float2*)d_ws;          // 768 * 2049 * 8 B = 12.6 MB
  hipLaunchKernelGGL(kfft_kernel, dim3(H), dim3(NT), 0, stream, kin, kf);
  hipLaunchKernelGGL(conv_kernel, dim3(BH), dim3(NT), 0, stream, x, kf, y, H);
}